// Round 8
// baseline (579.634 us; speedup 1.0000x reference)
//
#include <hip/hip_runtime.h>
#include <hip/hip_bf16.h>
#include <stdint.h>

#define NN 8192
#define DD 512

typedef unsigned short u16;
typedef __attribute__((ext_vector_type(8))) short short8;
typedef __attribute__((ext_vector_type(4))) float f32x4;

// async global->LDS, 16B per lane; LDS dest = wave-uniform base + lane*16
__device__ __forceinline__ void gld_lds16(const void* g, void* l) {
  __builtin_amdgcn_global_load_lds(
      (const __attribute__((address_space(1))) uint32_t*)(uintptr_t)g,
      (__attribute__((address_space(3))) uint32_t*)(uintptr_t)l,
      16, 0, 0);
}

__device__ __forceinline__ u16 f2bf(float f) {
  __hip_bfloat16 b = __float2bfloat16(f);
  return __builtin_bit_cast(u16, b);
}

__global__ void fill_kernel(float* __restrict__ p, int n, float v) {
  int i = blockIdx.x * 256 + threadIdx.x;
  int stride = gridDim.x * 256;
  for (; i < n; i += stride) p[i] = v;
}

__global__ void cvt4_kernel(const float4* __restrict__ src, ushort4* __restrict__ dst, int n4) {
  int i = blockIdx.x * 256 + threadIdx.x;
  int stride = gridDim.x * 256;
  for (; i < n4; i += stride) {
    float4 v = src[i];
    ushort4 o;
    o.x = f2bf(v.x); o.y = f2bf(v.y); o.z = f2bf(v.z); o.w = f2bf(v.w);
    dst[i] = o;
  }
}

// one wave per row: 1/||Wh_i||; also zeroes den[row]
__global__ void rownorm_kernel(const float* __restrict__ Wh, float* __restrict__ invn,
                               float* __restrict__ den) {
  int row = blockIdx.x;
  int l = threadIdx.x;  // 64
  const float4* p = (const float4*)(Wh + (size_t)row * DD);
  float4 a = p[l], b = p[l + 64];
  float s = a.x*a.x + a.y*a.y + a.z*a.z + a.w*a.w
          + b.x*b.x + b.y*b.y + b.z*b.z + b.w*b.w;
  #pragma unroll
  for (int off = 32; off; off >>= 1) s += __shfl_down(s, off);
  if (l == 0) {
    invn[row] = 1.0f / sqrtf(s);
    den[row] = 0.0f;
  }
}

// 64x64 tile: U = bf16(Wh * invn) (row-major) and WhT = bf16(Wh)^T
__global__ void u_wht_kernel(const float* __restrict__ Wh, const float* __restrict__ invn,
                             u16* __restrict__ U, u16* __restrict__ WhT) {
  __shared__ float tile[64][65];
  int i0 = blockIdx.x * 64, d0 = blockIdx.y * 64;
  int c = threadIdx.x & 63, rb = threadIdx.x >> 6;
  #pragma unroll
  for (int r = rb; r < 64; r += 4) {
    float v = Wh[(size_t)(i0 + r) * DD + d0 + c];
    tile[r][c] = v;
    U[(size_t)(i0 + r) * DD + d0 + c] = f2bf(v * invn[i0 + r]);
  }
  __syncthreads();
  #pragma unroll
  for (int r = rb; r < 64; r += 4) {
    WhT[(size_t)(d0 + r) * NN + i0 + c] = f2bf(tile[c][r]);
  }
}

// Wh-GEMM: C = A * B^T fp32, A:[M x K], B:[Nn x K] bf16. 128x128 tile, 256 thr.
__global__ void __launch_bounds__(256) gemm_wh(
    const u16* __restrict__ A, const u16* __restrict__ B,
    int Nn, int K, float* __restrict__ Cf)
{
  __shared__ __align__(16) u16 As[128 * 32];
  __shared__ __align__(16) u16 Bs[128 * 32];

  const int tid = threadIdx.x;
  const int w = tid >> 6;
  const int lane = tid & 63;
  const int lm = lane & 15;
  const int q = lane >> 4;
  const int row0 = blockIdx.y * 128;
  const int col0 = blockIdx.x * 128;
  const int RM = (w >> 1) * 64;
  const int RN = (w & 1) * 64;
  const int sr = tid >> 2;
  const int sk = (tid & 3) * 8;

  f32x4 acc[4][4];
  #pragma unroll
  for (int a_ = 0; a_ < 4; a_++)
    #pragma unroll
    for (int b_ = 0; b_ < 4; b_++)
      acc[a_][b_] = (f32x4){0.f, 0.f, 0.f, 0.f};

  const size_t Abase = (size_t)row0 * K;
  const size_t Bbase = (size_t)col0 * K;

  for (int k0 = 0; k0 < K; k0 += 32) {
    __syncthreads();
    gld_lds16(A + Abase + (size_t)sr * K + k0 + sk,        (char*)As + w * 1024);
    gld_lds16(A + Abase + (size_t)(sr + 64) * K + k0 + sk, (char*)As + 4096 + w * 1024);
    gld_lds16(B + Bbase + (size_t)sr * K + k0 + sk,        (char*)Bs + w * 1024);
    gld_lds16(B + Bbase + (size_t)(sr + 64) * K + k0 + sk, (char*)Bs + 4096 + w * 1024);
    __syncthreads();

    short8 af[4], bfr[4];
    #pragma unroll
    for (int mt = 0; mt < 4; mt++)
      af[mt] = *(const short8*)&As[(RM + mt * 16 + lm) * 32 + q * 8];
    #pragma unroll
    for (int nt = 0; nt < 4; nt++)
      bfr[nt] = *(const short8*)&Bs[(RN + nt * 16 + lm) * 32 + q * 8];

    #pragma unroll
    for (int mt = 0; mt < 4; mt++)
      #pragma unroll
      for (int nt = 0; nt < 4; nt++)
        acc[mt][nt] = __builtin_amdgcn_mfma_f32_16x16x32_bf16(af[mt], bfr[nt], acc[mt][nt], 0, 0, 0);
  }

  #pragma unroll
  for (int mt = 0; mt < 4; mt++) {
    const int ib = row0 + RM + mt * 16 + q * 4;
    #pragma unroll
    for (int rr = 0; rr < 4; rr++) {
      const int i = ib + rr;
      #pragma unroll
      for (int nt = 0; nt < 4; nt++) {
        const int jc = col0 + RN + nt * 16 + lm;
        Cf[(size_t)i * Nn + jc] = acc[mt][nt][rr];
      }
    }
  }
}

// sim-GEMM v6: full 64x64 grid, 128^2 tile, 4 waves, 4-deep buffer ring,
// counted vmcnt(12), XOR chunk swizzle both-sides, setprio. adj read directly
// with prefetch-before-prologue. Plateau ~178us over 5 structural variants.
__global__ void __launch_bounds__(256, 2) gemm_sim(
    const u16* __restrict__ U, const int* __restrict__ adj,
    u16* __restrict__ Pb, float* __restrict__ den)
{
  __shared__ __align__(16) char lds[65536];  // ring buf b at b*16384: A 8KB | B 8KB

  const int bj = blockIdx.x;
  const int bi = blockIdx.y;

  const int tid = threadIdx.x;
  const int w = tid >> 6;
  const int lane = tid & 63;
  const int lm = lane & 15;
  const int q = lane >> 4;
  const int row0 = bi * 128;
  const int col0 = bj * 128;
  const int RM = (w >> 1) * 64;
  const int RN = (w & 1) * 64;
  const bool diag = (bi == bj);

  const u16* Ab = U + (size_t)row0 * DD;
  const u16* Bb = U + (size_t)col0 * DD;

  const int srow = tid >> 2;                                  // 0..63
  const int sch8 = (((tid & 3) ^ ((tid >> 3) & 3)) << 3);     // element offset
  const int wofs = w << 10;                                   // per-wave LDS base

  const int rA = RM + lm;
  const int rB = RN + lm;
  const int aoff = rA * 64 + ((q ^ ((rA >> 1) & 3)) << 4);
  const int boff = 8192 + rB * 64 + ((q ^ ((rB >> 1) & 3)) << 4);

  f32x4 acc[4][4];
  #pragma unroll
  for (int a_ = 0; a_ < 4; a_++)
    #pragma unroll
    for (int b_ = 0; b_ < 4; b_++)
      acc[a_][b_] = (f32x4){0.f, 0.f, 0.f, 0.f};

  // adj batch-0 prefetch: oldest VMEM ops, retire with tile0's stage
  int na0[4][4], na1[4][4];
  {
    const int ib0 = row0 + RM + q * 4;
    #pragma unroll
    for (int rr = 0; rr < 4; rr++)
      #pragma unroll
      for (int nt = 0; nt < 4; nt++)
        na0[rr][nt] = adj[(size_t)(ib0 + rr) * NN + col0 + RN + nt * 16 + lm];
  }
  asm volatile("" ::: "memory");

#define SSTAGE(koff, dstoff)                                                      \
  do {                                                                            \
    char* d_ = lds + (dstoff);                                                    \
    gld_lds16(Ab + (size_t)srow * DD + (koff) + sch8,        d_ + wofs);          \
    gld_lds16(Ab + (size_t)(srow + 64) * DD + (koff) + sch8, d_ + 4096 + wofs);   \
    gld_lds16(Bb + (size_t)srow * DD + (koff) + sch8,        d_ + 8192 + wofs);   \
    gld_lds16(Bb + (size_t)(srow + 64) * DD + (koff) + sch8, d_ + 12288 + wofs);  \
  } while (0)

  SSTAGE(0, 0);
  SSTAGE(32, 16384);
  SSTAGE(64, 32768);
  SSTAGE(96, 49152);
  asm volatile("s_waitcnt vmcnt(12)" ::: "memory");
  asm volatile("s_barrier" ::: "memory");

#define STILE(T, CBOFF, DOSTAGE, VMC)                                             \
  do {                                                                            \
    const char* cb = lds + (CBOFF);                                               \
    short8 af[4], bfr[4];                                                         \
    _Pragma("unroll")                                                             \
    for (int m = 0; m < 4; m++)                                                   \
      af[m] = *(const short8*)(cb + aoff + m * 1024);                             \
    _Pragma("unroll")                                                             \
    for (int n = 0; n < 4; n++)                                                   \
      bfr[n] = *(const short8*)(cb + boff + n * 1024);                            \
    asm volatile("s_barrier" ::: "memory");                                       \
    asm volatile("s_waitcnt lgkmcnt(0)" ::: "memory");                            \
    __builtin_amdgcn_s_setprio(1);                                                \
    _Pragma("unroll")                                                             \
    for (int m = 0; m < 2; m++)                                                   \
      _Pragma("unroll")                                                           \
      for (int n = 0; n < 4; n++)                                                 \
        acc[m][n] = __builtin_amdgcn_mfma_f32_16x16x32_bf16(af[m], bfr[n], acc[m][n], 0, 0, 0); \
    __builtin_amdgcn_s_setprio(0);                                                \
    asm volatile("s_barrier" ::: "memory");                                       \
    if (DOSTAGE) SSTAGE(((T) + 4) * 32, (CBOFF));                                 \
    asm volatile("s_barrier" ::: "memory");                                       \
    __builtin_amdgcn_s_setprio(1);                                                \
    _Pragma("unroll")                                                             \
    for (int m = 2; m < 4; m++)                                                   \
      _Pragma("unroll")                                                           \
      for (int n = 0; n < 4; n++)                                                 \
        acc[m][n] = __builtin_amdgcn_mfma_f32_16x16x32_bf16(af[m], bfr[n], acc[m][n], 0, 0, 0); \
    __builtin_amdgcn_s_setprio(0);                                                \
    asm volatile("s_waitcnt " VMC ::: "memory");                                  \
    asm volatile("s_barrier" ::: "memory");                                       \
  } while (0)

  #pragma unroll 1
  for (int t = 0; t < 12; t += 4) {
    STILE(t + 0, 0,     1, "vmcnt(12)");
    STILE(t + 1, 16384, 1, "vmcnt(12)");
    STILE(t + 2, 32768, 1, "vmcnt(12)");
    STILE(t + 3, 49152, 1, "vmcnt(12)");
  }
  STILE(12, 0,     0, "vmcnt(8)");
  STILE(13, 16384, 0, "vmcnt(4)");
  STILE(14, 32768, 0, "vmcnt(0)");
  STILE(15, 49152, 0, "vmcnt(0)");
#undef STILE
#undef SSTAGE

#define EPI(MT, NAC, NAN, DOLOAD)                                                 \
  do {                                                                            \
    if (DOLOAD) {                                                                 \
      const int ibn = row0 + RM + ((MT) + 1) * 16 + q * 4;                        \
      _Pragma("unroll")                                                           \
      for (int rr = 0; rr < 4; rr++)                                              \
        _Pragma("unroll")                                                         \
        for (int nt = 0; nt < 4; nt++)                                            \
          NAN[rr][nt] = adj[(size_t)(ibn + rr) * NN + col0 + RN + nt * 16 + lm];  \
    }                                                                             \
    const int ibc = row0 + RM + (MT) * 16 + q * 4;                                \
    _Pragma("unroll")                                                             \
    for (int rr = 0; rr < 4; rr++) {                                              \
      const int i = ibc + rr;                                                     \
      float psum = 0.f;                                                           \
      _Pragma("unroll")                                                           \
      for (int nt = 0; nt < 4; nt++) {                                            \
        const int jc = col0 + RN + nt * 16 + lm;                                  \
        const float ev = __expf(acc[MT][nt][rr]);                                 \
        const bool on = (NAC[rr][nt] != 0) || (diag && i == jc);                  \
        const float p = on ? ev : 0.0f;                                           \
        psum += p;                                                                \
        Pb[(size_t)i * NN + jc] = f2bf(p);                                        \
      }                                                                           \
      _Pragma("unroll")                                                           \
      for (int off = 8; off; off >>= 1) psum += __shfl_down(psum, off, 16);       \
      if (lm == 0) atomicAdd(&den[i], psum);                                      \
    }                                                                             \
  } while (0)

  EPI(0, na0, na1, 1);
  EPI(1, na1, na0, 1);
  EPI(2, na0, na1, 1);
  EPI(3, na1, na0, 0);
#undef EPI
}

// out-GEMM v3: 128 rows x FULL N=512 tile, split-K=4 (grid 64x4 = 256 blocks).
// P (134 MB, not cache-resident) is read EXACTLY ONCE (v2's 256-col split read
// it twice = 268 MB); WhT re-reads (2 MB panel per z, shared by 64 same-z
// blocks) are L2/L3-resident. Proven schedule: XOR chunk swizzle both-sides,
// phase-split 16+16 MFMA, counted vmcnt(5) (5 loads/stage: A=1, B=4), setprio.
// 80 KB LDS dbuf, acc[4][8] (128 VGPR), 8 waves (2M x 4N). Same per-element
// MFMA k-chain order as v2 -> bit-identical partials.
__global__ void __launch_bounds__(512, 2) gemm_out3(
    const u16* __restrict__ P_,   // P [NN x NN]
    const u16* __restrict__ Wt,   // WhT [DD x NN]
    u16* __restrict__ p0, u16* __restrict__ p1,
    u16* __restrict__ p2, u16* __restrict__ p3)
{
  __shared__ __align__(16) char lds[81920];  // buf b at b*40960: A 8KB | B 32KB

  const int tid = threadIdx.x;
  const int lane = tid & 63;
  const int lm = lane & 15;
  const int q = lane >> 4;
  const int w = tid >> 6;       // 0..7
  const int wm = w >> 2;        // 0..1 -> 64-row group
  const int wn = w & 3;         // 0..3 -> 128-col group
  const int row0 = blockIdx.x * 128;   // i block
  const int z = blockIdx.y;            // split-K
  const int kBegin = z * (NN / 4);
  const int NT = (NN / 4) / 32;        // 64 K-tiles

  const u16* Ab = P_ + (size_t)row0 * NN;

  // staging: 512 threads, row tid>>2 (0..127), slot tid&3;
  // source content chunk = slot ^ ((row>>1)&3)
  const int srow = tid >> 2;                                  // 0..127
  const int sch8 = (((tid & 3) ^ ((tid >> 3) & 3)) << 3);     // element offset
  const int wofs = w << 10;                                   // per-wave LDS base

  // read-side: logical (r, chunk c) at byte r*64 + ((c ^ ((r>>1)&3))<<4);
  // key invariant under r += 16 (and +128 for B's d-groups), fold once.
  const int rA = wm * 64 + lm;          // 0..127
  const int rB = wn * 128 + lm;         // 0..511
  const int aoff = rA * 64 + ((q ^ ((rA >> 1) & 3)) << 4);
  const int boff = 8192 + rB * 64 + ((q ^ ((rB >> 1) & 3)) << 4);

  f32x4 acc[4][8];
  #pragma unroll
  for (int m = 0; m < 4; m++)
    #pragma unroll
    for (int n = 0; n < 8; n++)
      acc[m][n] = (f32x4){0.f, 0.f, 0.f, 0.f};

#define STAGE5(koff, dstoff)                                                      \
  do {                                                                            \
    char* d_ = lds + (dstoff);                                                    \
    gld_lds16(Ab + (size_t)srow * NN + (koff) + sch8,              d_ + wofs);    \
    gld_lds16(Wt + (size_t)srow * NN + (koff) + sch8,              d_ + 8192 + wofs);  \
    gld_lds16(Wt + (size_t)(srow + 128) * NN + (koff) + sch8,      d_ + 16384 + wofs); \
    gld_lds16(Wt + (size_t)(srow + 256) * NN + (koff) + sch8,      d_ + 24576 + wofs); \
    gld_lds16(Wt + (size_t)(srow + 384) * NN + (koff) + sch8,      d_ + 32768 + wofs); \
  } while (0)

  // prologue: tile 0 -> buf0, tile 1 -> buf1; drain tile 0, leave tile 1's 5
  STAGE5(kBegin, 0);
  STAGE5(kBegin + 32, 40960);
  asm volatile("s_waitcnt vmcnt(5)" ::: "memory");
  asm volatile("s_barrier" ::: "memory");

#define TILE(T, CBOFF)                                                            \
  do {                                                                            \
    const char* cb = lds + (CBOFF);                                               \
    short8 af[4], bf_[8];                                                         \
    _Pragma("unroll")                                                             \
    for (int m = 0; m < 4; m++)                                                   \
      af[m] = *(const short8*)(cb + aoff + m * 1024);                             \
    _Pragma("unroll")                                                             \
    for (int n = 0; n < 8; n++)                                                   \
      bf_[n] = *(const short8*)(cb + boff + n * 1024);                            \
    asm volatile("s_barrier" ::: "memory");                                       \
    asm volatile("s_waitcnt lgkmcnt(0)" ::: "memory");                            \
    __builtin_amdgcn_s_setprio(1);                                                \
    _Pragma("unroll")                                                             \
    for (int m = 0; m < 2; m++)                                                   \
      _Pragma("unroll")                                                           \
      for (int n = 0; n < 8; n++)                                                 \
        acc[m][n] = __builtin_amdgcn_mfma_f32_16x16x32_bf16(af[m], bf_[n], acc[m][n], 0, 0, 0); \
    __builtin_amdgcn_s_setprio(0);                                                \
    asm volatile("s_barrier" ::: "memory");                                       \
    if ((T) + 2 < NT) STAGE5(kBegin + ((T) + 2) * 32, CBOFF);                     \
    asm volatile("s_barrier" ::: "memory");                                       \
    __builtin_amdgcn_s_setprio(1);                                                \
    _Pragma("unroll")                                                             \
    for (int m = 2; m < 4; m++)                                                   \
      _Pragma("unroll")                                                           \
      for (int n = 0; n < 8; n++)                                                 \
        acc[m][n] = __builtin_amdgcn_mfma_f32_16x16x32_bf16(af[m], bf_[n], acc[m][n], 0, 0, 0); \
    __builtin_amdgcn_s_setprio(0);                                                \
    if ((T) + 2 < NT) { asm volatile("s_waitcnt vmcnt(5)" ::: "memory"); }        \
    else              { asm volatile("s_waitcnt vmcnt(0)" ::: "memory"); }        \
    asm volatile("s_barrier" ::: "memory");                                       \
  } while (0)

  #pragma unroll 1
  for (int t = 0; t < NT; t += 2) {
    TILE(t, 0);
    TILE(t + 1, 40960);
  }
#undef TILE
#undef STAGE5

  u16* const part = (z == 0) ? p0 : (z == 1) ? p1 : (z == 2) ? p2 : p3;
  #pragma unroll
  for (int m = 0; m < 4; m++) {
    const int ib = row0 + wm * 64 + m * 16 + q * 4;
    #pragma unroll
    for (int rr = 0; rr < 4; rr++) {
      const int i = ib + rr;
      #pragma unroll
      for (int n = 0; n < 8; n++) {
        const int dc = wn * 128 + n * 16 + lm;
        part[(size_t)i * DD + dc] = f2bf(acc[m][n][rr]);
      }
    }
  }
}

// out = (sum of 4 bf16 partials) / den[row]; each thread handles 8 cols
__global__ void reduce4_kernel(const uint4* __restrict__ p0, const uint4* __restrict__ p1,
                               const uint4* __restrict__ p2, const uint4* __restrict__ p3,
                               const float* __restrict__ den, float4* __restrict__ out) {
  const int idx = blockIdx.x * 256 + threadIdx.x;   // NN*DD/8 units of 8 cols
  const int row = idx >> 6;                          // 64 units per row
  const float dinv = 1.0f / den[row];
  float s[8] = {0, 0, 0, 0, 0, 0, 0, 0};
  #pragma unroll
  for (int zp = 0; zp < 4; zp++) {
    const uint4 u = (zp == 0 ? p0 : zp == 1 ? p1 : zp == 2 ? p2 : p3)[idx];
    s[0] += __uint_as_float(u.x << 16); s[1] += __uint_as_float(u.x & 0xffff0000u);
    s[2] += __uint_as_float(u.y << 16); s[3] += __uint_as_float(u.y & 0xffff0000u);
    s[4] += __uint_as_float(u.z << 16); s[5] += __uint_as_float(u.z & 0xffff0000u);
    s[6] += __uint_as_float(u.w << 16); s[7] += __uint_as_float(u.w & 0xffff0000u);
  }
  float4 o0 = {s[0] * dinv, s[1] * dinv, s[2] * dinv, s[3] * dinv};
  float4 o1 = {s[4] * dinv, s[5] * dinv, s[6] * dinv, s[7] * dinv};
  out[idx * 2] = o0;
  out[idx * 2 + 1] = o1;
}

extern "C" void kernel_launch(void* const* d_in, const int* in_sizes, int n_in,
                              void* d_out, int out_size, void* d_ws, size_t ws_size,
                              hipStream_t stream) {
  const float* h = (const float*)d_in[0];
  const int* adj = (const int*)d_in[1];
  const float* W = (const float*)d_in[2];
  float* out = (float*)d_out;

  const size_t SZ_P    = (size_t)NN * NN * 2;      // 134.2 MB
  const size_t SZ_X0   = (size_t)NN * NN / 8;      // 8.4 MB  (-> part0)
  const size_t SZ_WHT  = (size_t)DD * NN * 2;      // 8.4 MB
  const size_t SZ_HB   = (size_t)NN * DD * 2;      // 8.4 MB  (-> part2)
  const size_t SZ_WB   = (size_t)DD * DD * 2;      // 0.5 MB
  const size_t SZ_U    = (size_t)NN * DD * 2;      // 8.4 MB  (-> part1)
  const size_t SZ_P3   = (size_t)NN * DD * 2;      // 8.4 MB  (part3)
  const size_t NEEDED  = SZ_P + SZ_X0 + SZ_WHT + SZ_HB + SZ_WB + SZ_U + SZ_P3 + 2 * (size_t)NN * 4;

  if (ws_size < NEEDED) {
    fill_kernel<<<256, 256, 0, stream>>>(out, out_size, 12345.0f);
    return;
  }

  char* ws = (char*)d_ws;
  size_t off = 0;
  u16*   P    = (u16*)(ws + off); off += SZ_P;
  u16*   x0   = (u16*)(ws + off); off += SZ_X0;
  u16*   WhT  = (u16*)(ws + off); off += SZ_WHT;
  u16*   hb   = (u16*)(ws + off); off += SZ_HB;
  u16*   Wb   = (u16*)(ws + off); off += SZ_WB;
  u16*   U    = (u16*)(ws + off); off += SZ_U;
  u16*   p3   = (u16*)(ws + off); off += SZ_P3;
  float* invn = (float*)(ws + off);
  float* den  = invn + NN;

  // Wh fp32 (16.8 MB) aliases the P prefix: dead before sim writes P.
  float* Wh = (float*)P;
  // split-K partials reuse regions dead after the sim-GEMM:
  u16* part0 = x0;
  u16* part1 = U;
  u16* part2 = hb;
  u16* part3 = p3;

  cvt4_kernel<<<1024, 256, 0, stream>>>((const float4*)h, (ushort4*)hb, NN * DD / 4);
  cvt4_kernel<<<256, 256, 0, stream>>>((const float4*)W, (ushort4*)Wb, DD * DD / 4);
  // Wh = h @ W^T
  gemm_wh<<<dim3(DD / 128, NN / 128), 256, 0, stream>>>(hb, Wb, DD, DD, Wh);
  rownorm_kernel<<<NN, 64, 0, stream>>>(Wh, invn, den);
  u_wht_kernel<<<dim3(NN / 64, DD / 64), 256, 0, stream>>>(Wh, invn, U, WhT);
  // P = mask ? exp(U U^T) : 0 (bf16), full grid, 4-deep ring prefetch, fused den
  gemm_sim<<<dim3(NN / 128, NN / 128), 256, 0, stream>>>(U, adj, P, den);
  // out partials: 128 x full-N tile (P read once), split-K=4
  gemm_out3<<<dim3(NN / 128, 4), 512, 0, stream>>>(P, WhT, part0, part1, part2, part3);
  // out = (p0+p1+p2+p3) / den
  reduce4_kernel<<<NN * DD / 8 / 256, 256, 0, stream>>>(
      (const uint4*)part0, (const uint4*)part1, (const uint4*)part2, (const uint4*)part3,
      den, (float4*)out);
}

// Round 9
// 570.394 us; speedup vs baseline: 1.0162x; 1.0162x over previous
//
#include <hip/hip_runtime.h>
#include <hip/hip_bf16.h>
#include <stdint.h>

#define NN 8192
#define DD 512

typedef unsigned short u16;
typedef __attribute__((ext_vector_type(8))) short short8;
typedef __attribute__((ext_vector_type(4))) float f32x4;

// async global->LDS, 16B per lane; LDS dest = wave-uniform base + lane*16
__device__ __forceinline__ void gld_lds16(const void* g, void* l) {
  __builtin_amdgcn_global_load_lds(
      (const __attribute__((address_space(1))) uint32_t*)(uintptr_t)g,
      (__attribute__((address_space(3))) uint32_t*)(uintptr_t)l,
      16, 0, 0);
}

__device__ __forceinline__ u16 f2bf(float f) {
  __hip_bfloat16 b = __float2bfloat16(f);
  return __builtin_bit_cast(u16, b);
}

__global__ void fill_kernel(float* __restrict__ p, int n, float v) {
  int i = blockIdx.x * 256 + threadIdx.x;
  int stride = gridDim.x * 256;
  for (; i < n; i += stride) p[i] = v;
}

__global__ void cvt4_kernel(const float4* __restrict__ src, ushort4* __restrict__ dst, int n4) {
  int i = blockIdx.x * 256 + threadIdx.x;
  int stride = gridDim.x * 256;
  for (; i < n4; i += stride) {
    float4 v = src[i];
    ushort4 o;
    o.x = f2bf(v.x); o.y = f2bf(v.y); o.z = f2bf(v.z); o.w = f2bf(v.w);
    dst[i] = o;
  }
}

// one wave per row: 1/||Wh_i||; also zeroes den[row]
__global__ void rownorm_kernel(const float* __restrict__ Wh, float* __restrict__ invn,
                               float* __restrict__ den) {
  int row = blockIdx.x;
  int l = threadIdx.x;  // 64
  const float4* p = (const float4*)(Wh + (size_t)row * DD);
  float4 a = p[l], b = p[l + 64];
  float s = a.x*a.x + a.y*a.y + a.z*a.z + a.w*a.w
          + b.x*b.x + b.y*b.y + b.z*b.z + b.w*b.w;
  #pragma unroll
  for (int off = 32; off; off >>= 1) s += __shfl_down(s, off);
  if (l == 0) {
    invn[row] = 1.0f / sqrtf(s);
    den[row] = 0.0f;
  }
}

// 64x64 tile: U = bf16(Wh * invn) (row-major) and WhT = bf16(Wh)^T
__global__ void u_wht_kernel(const float* __restrict__ Wh, const float* __restrict__ invn,
                             u16* __restrict__ U, u16* __restrict__ WhT) {
  __shared__ float tile[64][65];
  int i0 = blockIdx.x * 64, d0 = blockIdx.y * 64;
  int c = threadIdx.x & 63, rb = threadIdx.x >> 6;
  #pragma unroll
  for (int r = rb; r < 64; r += 4) {
    float v = Wh[(size_t)(i0 + r) * DD + d0 + c];
    tile[r][c] = v;
    U[(size_t)(i0 + r) * DD + d0 + c] = f2bf(v * invn[i0 + r]);
  }
  __syncthreads();
  #pragma unroll
  for (int r = rb; r < 64; r += 4) {
    WhT[(size_t)(d0 + r) * NN + i0 + c] = f2bf(tile[c][r]);
  }
}

// Wh-GEMM: C = A * B^T fp32, A:[M x K], B:[Nn x K] bf16. 128x128 tile, 256 thr.
__global__ void __launch_bounds__(256) gemm_wh(
    const u16* __restrict__ A, const u16* __restrict__ B,
    int Nn, int K, float* __restrict__ Cf)
{
  __shared__ __align__(16) u16 As[128 * 32];
  __shared__ __align__(16) u16 Bs[128 * 32];

  const int tid = threadIdx.x;
  const int w = tid >> 6;
  const int lane = tid & 63;
  const int lm = lane & 15;
  const int q = lane >> 4;
  const int row0 = blockIdx.y * 128;
  const int col0 = blockIdx.x * 128;
  const int RM = (w >> 1) * 64;
  const int RN = (w & 1) * 64;
  const int sr = tid >> 2;
  const int sk = (tid & 3) * 8;

  f32x4 acc[4][4];
  #pragma unroll
  for (int a_ = 0; a_ < 4; a_++)
    #pragma unroll
    for (int b_ = 0; b_ < 4; b_++)
      acc[a_][b_] = (f32x4){0.f, 0.f, 0.f, 0.f};

  const size_t Abase = (size_t)row0 * K;
  const size_t Bbase = (size_t)col0 * K;

  for (int k0 = 0; k0 < K; k0 += 32) {
    __syncthreads();
    gld_lds16(A + Abase + (size_t)sr * K + k0 + sk,        (char*)As + w * 1024);
    gld_lds16(A + Abase + (size_t)(sr + 64) * K + k0 + sk, (char*)As + 4096 + w * 1024);
    gld_lds16(B + Bbase + (size_t)sr * K + k0 + sk,        (char*)Bs + w * 1024);
    gld_lds16(B + Bbase + (size_t)(sr + 64) * K + k0 + sk, (char*)Bs + 4096 + w * 1024);
    __syncthreads();

    short8 af[4], bfr[4];
    #pragma unroll
    for (int mt = 0; mt < 4; mt++)
      af[mt] = *(const short8*)&As[(RM + mt * 16 + lm) * 32 + q * 8];
    #pragma unroll
    for (int nt = 0; nt < 4; nt++)
      bfr[nt] = *(const short8*)&Bs[(RN + nt * 16 + lm) * 32 + q * 8];

    #pragma unroll
    for (int mt = 0; mt < 4; mt++)
      #pragma unroll
      for (int nt = 0; nt < 4; nt++)
        acc[mt][nt] = __builtin_amdgcn_mfma_f32_16x16x32_bf16(af[mt], bfr[nt], acc[mt][nt], 0, 0, 0);
  }

  #pragma unroll
  for (int mt = 0; mt < 4; mt++) {
    const int ib = row0 + RM + mt * 16 + q * 4;
    #pragma unroll
    for (int rr = 0; rr < 4; rr++) {
      const int i = ib + rr;
      #pragma unroll
      for (int nt = 0; nt < 4; nt++) {
        const int jc = col0 + RN + nt * 16 + lm;
        Cf[(size_t)i * Nn + jc] = acc[mt][nt][rr];
      }
    }
  }
}

// sim-GEMM v7: full 64x64 grid, 128^2 tile, 4 waves, 4-deep ring, ONE BARRIER
// PER TILE. Safety proof: stage at tile T targets buf (T+3)&3 == (T-1)&3, whose
// readers all executed lgkmcnt(0) (data in registers) before passing tile T-1's
// end barrier -> any post-barrier stage is race-free. Cross-wave stage
// visibility: each wave vmcnts its own stage loads before the end barrier, the
// barrier publishes to all. Per tile: {8 ds_read; stage(T+3); lgkm0; 16 MFMA;
// vmcnt(8); barrier}. v6 had 4 barriers/tile; measured critical path 830
// cyc/tile vs ~250 cyc of work -> barrier sync is the prime suspect.
__global__ void __launch_bounds__(256, 2) gemm_sim(
    const u16* __restrict__ U, const int* __restrict__ adj,
    u16* __restrict__ Pb, float* __restrict__ den)
{
  __shared__ __align__(16) char lds[65536];  // ring buf b at b*16384: A 8KB | B 8KB

  const int bj = blockIdx.x;
  const int bi = blockIdx.y;

  const int tid = threadIdx.x;
  const int w = tid >> 6;
  const int lane = tid & 63;
  const int lm = lane & 15;
  const int q = lane >> 4;
  const int row0 = bi * 128;
  const int col0 = bj * 128;
  const int RM = (w >> 1) * 64;
  const int RN = (w & 1) * 64;
  const bool diag = (bi == bj);

  const u16* Ab = U + (size_t)row0 * DD;
  const u16* Bb = U + (size_t)col0 * DD;

  const int srow = tid >> 2;                                  // 0..63
  const int sch8 = (((tid & 3) ^ ((tid >> 3) & 3)) << 3);     // element offset
  const int wofs = w << 10;                                   // per-wave LDS base

  const int rA = RM + lm;
  const int rB = RN + lm;
  const int aoff = rA * 64 + ((q ^ ((rA >> 1) & 3)) << 4);
  const int boff = 8192 + rB * 64 + ((q ^ ((rB >> 1) & 3)) << 4);

  f32x4 acc[4][4];
  #pragma unroll
  for (int a_ = 0; a_ < 4; a_++)
    #pragma unroll
    for (int b_ = 0; b_ < 4; b_++)
      acc[a_][b_] = (f32x4){0.f, 0.f, 0.f, 0.f};

  // adj batch-0 prefetch: oldest VMEM ops; drained by the prologue vmcnt(8)
  int na0[4][4], na1[4][4];
  {
    const int ib0 = row0 + RM + q * 4;
    #pragma unroll
    for (int rr = 0; rr < 4; rr++)
      #pragma unroll
      for (int nt = 0; nt < 4; nt++)
        na0[rr][nt] = adj[(size_t)(ib0 + rr) * NN + col0 + RN + nt * 16 + lm];
  }
  asm volatile("" ::: "memory");

#define SSTAGE(koff, dstoff)                                                      \
  do {                                                                            \
    char* d_ = lds + (dstoff);                                                    \
    gld_lds16(Ab + (size_t)srow * DD + (koff) + sch8,        d_ + wofs);          \
    gld_lds16(Ab + (size_t)(srow + 64) * DD + (koff) + sch8, d_ + 4096 + wofs);   \
    gld_lds16(Bb + (size_t)srow * DD + (koff) + sch8,        d_ + 8192 + wofs);   \
    gld_lds16(Bb + (size_t)(srow + 64) * DD + (koff) + sch8, d_ + 12288 + wofs);  \
  } while (0)

  // prologue: tiles 0..2 -> bufs 0..2 (buf3 first written by tile0's stage).
  // vmcnt(8) drains adj(16)+stage0, leaves stage1+stage2 (newest 8) in flight.
  SSTAGE(0, 0);
  SSTAGE(32, 16384);
  SSTAGE(64, 32768);
  asm volatile("s_waitcnt vmcnt(8)" ::: "memory");
  asm volatile("s_barrier" ::: "memory");

  // Tile T: reads(buf T&3); stage(T+3 -> buf (T+3)&3); lgkm0; 16 MFMA;
  // vmcnt(VMC: T+1's stage complete); barrier.
#define STILE(T, CBOFF, SBOFF, DOSTAGE, VMC)                                      \
  do {                                                                            \
    const char* cb = lds + (CBOFF);                                               \
    short8 af[4], bfr[4];                                                         \
    _Pragma("unroll")                                                             \
    for (int m = 0; m < 4; m++)                                                   \
      af[m] = *(const short8*)(cb + aoff + m * 1024);                             \
    _Pragma("unroll")                                                             \
    for (int n = 0; n < 4; n++)                                                   \
      bfr[n] = *(const short8*)(cb + boff + n * 1024);                            \
    if (DOSTAGE) SSTAGE(((T) + 3) * 32, (SBOFF));                                 \
    asm volatile("s_waitcnt lgkmcnt(0)" ::: "memory");                            \
    __builtin_amdgcn_s_setprio(1);                                                \
    _Pragma("unroll")                                                             \
    for (int m = 0; m < 4; m++)                                                   \
      _Pragma("unroll")                                                           \
      for (int n = 0; n < 4; n++)                                                 \
        acc[m][n] = __builtin_amdgcn_mfma_f32_16x16x32_bf16(af[m], bfr[n], acc[m][n], 0, 0, 0); \
    __builtin_amdgcn_s_setprio(0);                                                \
    asm volatile("s_waitcnt " VMC ::: "memory");                                  \
    asm volatile("s_barrier" ::: "memory");                                       \
  } while (0)

  #pragma unroll 1
  for (int t = 0; t < 12; t += 4) {
    STILE(t + 0, 0,     49152, 1, "vmcnt(8)");
    STILE(t + 1, 16384, 0,     1, "vmcnt(8)");
    STILE(t + 2, 32768, 16384, 1, "vmcnt(8)");
    STILE(t + 3, 49152, 32768, 1, "vmcnt(8)");
  }
  STILE(12, 0,     49152, 1, "vmcnt(8)");
  STILE(13, 16384, 0,     0, "vmcnt(4)");
  STILE(14, 32768, 0,     0, "vmcnt(0)");
  STILE(15, 49152, 0,     0, "vmcnt(0)");
#undef STILE
#undef SSTAGE

  // epilogue: C/D layout col = lm, row = q*4 + rr; adj batches pipelined 1-deep
#define EPI(MT, NAC, NAN, DOLOAD)                                                 \
  do {                                                                            \
    if (DOLOAD) {                                                                 \
      const int ibn = row0 + RM + ((MT) + 1) * 16 + q * 4;                        \
      _Pragma("unroll")                                                           \
      for (int rr = 0; rr < 4; rr++)                                              \
        _Pragma("unroll")                                                         \
        for (int nt = 0; nt < 4; nt++)                                            \
          NAN[rr][nt] = adj[(size_t)(ibn + rr) * NN + col0 + RN + nt * 16 + lm];  \
    }                                                                             \
    const int ibc = row0 + RM + (MT) * 16 + q * 4;                                \
    _Pragma("unroll")                                                             \
    for (int rr = 0; rr < 4; rr++) {                                              \
      const int i = ibc + rr;                                                     \
      float psum = 0.f;                                                           \
      _Pragma("unroll")                                                           \
      for (int nt = 0; nt < 4; nt++) {                                            \
        const int jc = col0 + RN + nt * 16 + lm;                                  \
        const float ev = __expf(acc[MT][nt][rr]);                                 \
        const bool on = (NAC[rr][nt] != 0) || (diag && i == jc);                  \
        const float p = on ? ev : 0.0f;                                           \
        psum += p;                                                                \
        Pb[(size_t)i * NN + jc] = f2bf(p);                                        \
      }                                                                           \
      _Pragma("unroll")                                                           \
      for (int off = 8; off; off >>= 1) psum += __shfl_down(psum, off, 16);       \
      if (lm == 0) atomicAdd(&den[i], psum);                                      \
    }                                                                             \
  } while (0)

  EPI(0, na0, na1, 1);
  EPI(1, na1, na0, 1);
  EPI(2, na0, na1, 1);
  EPI(3, na1, na0, 0);
#undef EPI
}

// out-GEMM v2 (round-7 best): 256x256 tile, BK=32, 8 waves, split-K=4.
// P's second read is L3-served (134 MB < 256 MB L3) -- round-8's read-once
// variant regressed, reverted. Counted vmcnt(4), XOR chunk swizzle, setprio.
__global__ void __launch_bounds__(512, 2) gemm_out2(
    const u16* __restrict__ P_,   // P [NN x NN]
    const u16* __restrict__ Wt,   // WhT [DD x NN]
    u16* __restrict__ p0, u16* __restrict__ p1,
    u16* __restrict__ p2, u16* __restrict__ p3)
{
  __shared__ __align__(16) char lds[65536];  // buf b at b*32768: A 16KB | B 16KB

  const int tid = threadIdx.x;
  const int lane = tid & 63;
  const int lm = lane & 15;
  const int q = lane >> 4;
  const int w = tid >> 6;       // 0..7
  const int wm = w >> 2;        // 0..1 -> 128 rows
  const int wn = w & 3;         // 0..3 -> 64 cols
  const int row0 = blockIdx.x * 256;   // i block
  const int col0 = blockIdx.y * 256;   // d block
  const int z = blockIdx.z;            // split-K
  const int kBegin = z * (NN / 4);
  const int NT = (NN / 4) / 32;        // 64 K-tiles

  const u16* Ab = P_ + (size_t)row0 * NN;
  const u16* Bb = Wt + (size_t)col0 * NN;

  const int srow = tid >> 2;                                  // 0..127
  const int sch8 = (((tid & 3) ^ ((tid >> 3) & 3)) << 3);     // element offset
  const int wofs = (tid >> 6) << 10;                          // per-wave LDS base

  const int rA = wm * 128 + lm;
  const int rB = wn * 64 + lm;
  const int aoff = rA * 64 + ((q ^ ((rA >> 1) & 3)) << 4);
  const int boff = 16384 + rB * 64 + ((q ^ ((rB >> 1) & 3)) << 4);

  f32x4 acc[8][4];
  #pragma unroll
  for (int m = 0; m < 8; m++)
    #pragma unroll
    for (int n = 0; n < 4; n++)
      acc[m][n] = (f32x4){0.f, 0.f, 0.f, 0.f};

#define STAGE4(koff, dstoff)                                                      \
  do {                                                                            \
    char* d_ = lds + (dstoff);                                                    \
    gld_lds16(Ab + (size_t)srow * NN + (koff) + sch8,         d_ + wofs);         \
    gld_lds16(Ab + (size_t)(srow + 128) * NN + (koff) + sch8, d_ + 8192 + wofs);  \
    gld_lds16(Bb + (size_t)srow * NN + (koff) + sch8,         d_ + 16384 + wofs); \
    gld_lds16(Bb + (size_t)(srow + 128) * NN + (koff) + sch8, d_ + 24576 + wofs); \
  } while (0)

  STAGE4(kBegin, 0);
  STAGE4(kBegin + 32, 32768);
  asm volatile("s_waitcnt vmcnt(4)" ::: "memory");
  asm volatile("s_barrier" ::: "memory");

#define TILE(T, CBOFF)                                                            \
  do {                                                                            \
    const char* cb = lds + (CBOFF);                                               \
    short8 af[8], bf_[4];                                                         \
    _Pragma("unroll")                                                             \
    for (int m = 0; m < 8; m++)                                                   \
      af[m] = *(const short8*)(cb + aoff + m * 1024);                             \
    _Pragma("unroll")                                                             \
    for (int n = 0; n < 4; n++)                                                   \
      bf_[n] = *(const short8*)(cb + boff + n * 1024);                            \
    asm volatile("s_barrier" ::: "memory");                                       \
    asm volatile("s_waitcnt lgkmcnt(0)" ::: "memory");                            \
    __builtin_amdgcn_s_setprio(1);                                                \
    _Pragma("unroll")                                                             \
    for (int m = 0; m < 4; m++)                                                   \
      _Pragma("unroll")                                                           \
      for (int n = 0; n < 4; n++)                                                 \
        acc[m][n] = __builtin_amdgcn_mfma_f32_16x16x32_bf16(af[m], bf_[n], acc[m][n], 0, 0, 0); \
    __builtin_amdgcn_s_setprio(0);                                                \
    asm volatile("s_barrier" ::: "memory");                                       \
    if ((T) + 2 < NT) STAGE4(kBegin + ((T) + 2) * 32, CBOFF);                     \
    asm volatile("s_barrier" ::: "memory");                                       \
    __builtin_amdgcn_s_setprio(1);                                                \
    _Pragma("unroll")                                                             \
    for (int m = 4; m < 8; m++)                                                   \
      _Pragma("unroll")                                                           \
      for (int n = 0; n < 4; n++)                                                 \
        acc[m][n] = __builtin_amdgcn_mfma_f32_16x16x32_bf16(af[m], bf_[n], acc[m][n], 0, 0, 0); \
    __builtin_amdgcn_s_setprio(0);                                                \
    if ((T) + 2 < NT) { asm volatile("s_waitcnt vmcnt(4)" ::: "memory"); }        \
    else              { asm volatile("s_waitcnt vmcnt(0)" ::: "memory"); }        \
    asm volatile("s_barrier" ::: "memory");                                       \
  } while (0)

  #pragma unroll 1
  for (int t = 0; t < NT; t += 2) {
    TILE(t, 0);
    TILE(t + 1, 32768);
  }
#undef TILE
#undef STAGE4

  u16* const part = (z == 0) ? p0 : (z == 1) ? p1 : (z == 2) ? p2 : p3;
  #pragma unroll
  for (int m = 0; m < 8; m++) {
    const int ib = row0 + wm * 128 + m * 16 + q * 4;
    #pragma unroll
    for (int rr = 0; rr < 4; rr++) {
      const int i = ib + rr;
      #pragma unroll
      for (int n = 0; n < 4; n++) {
        const int dc = col0 + wn * 64 + n * 16 + lm;
        part[(size_t)i * DD + dc] = f2bf(acc[m][n][rr]);
      }
    }
  }
}

// out = (sum of 4 bf16 partials) / den[row]; each thread handles 8 cols
__global__ void reduce4_kernel(const uint4* __restrict__ p0, const uint4* __restrict__ p1,
                               const uint4* __restrict__ p2, const uint4* __restrict__ p3,
                               const float* __restrict__ den, float4* __restrict__ out) {
  const int idx = blockIdx.x * 256 + threadIdx.x;   // NN*DD/8 units of 8 cols
  const int row = idx >> 6;                          // 64 units per row
  const float dinv = 1.0f / den[row];
  float s[8] = {0, 0, 0, 0, 0, 0, 0, 0};
  #pragma unroll
  for (int zp = 0; zp < 4; zp++) {
    const uint4 u = (zp == 0 ? p0 : zp == 1 ? p1 : zp == 2 ? p2 : p3)[idx];
    s[0] += __uint_as_float(u.x << 16); s[1] += __uint_as_float(u.x & 0xffff0000u);
    s[2] += __uint_as_float(u.y << 16); s[3] += __uint_as_float(u.y & 0xffff0000u);
    s[4] += __uint_as_float(u.z << 16); s[5] += __uint_as_float(u.z & 0xffff0000u);
    s[6] += __uint_as_float(u.w << 16); s[7] += __uint_as_float(u.w & 0xffff0000u);
  }
  float4 o0 = {s[0] * dinv, s[1] * dinv, s[2] * dinv, s[3] * dinv};
  float4 o1 = {s[4] * dinv, s[5] * dinv, s[6] * dinv, s[7] * dinv};
  out[idx * 2] = o0;
  out[idx * 2 + 1] = o1;
}

extern "C" void kernel_launch(void* const* d_in, const int* in_sizes, int n_in,
                              void* d_out, int out_size, void* d_ws, size_t ws_size,
                              hipStream_t stream) {
  const float* h = (const float*)d_in[0];
  const int* adj = (const int*)d_in[1];
  const float* W = (const float*)d_in[2];
  float* out = (float*)d_out;

  const size_t SZ_P    = (size_t)NN * NN * 2;      // 134.2 MB
  const size_t SZ_X0   = (size_t)NN * NN / 8;      // 8.4 MB  (-> part0)
  const size_t SZ_WHT  = (size_t)DD * NN * 2;      // 8.4 MB
  const size_t SZ_HB   = (size_t)NN * DD * 2;      // 8.4 MB  (-> part2)
  const size_t SZ_WB   = (size_t)DD * DD * 2;      // 0.5 MB
  const size_t SZ_U    = (size_t)NN * DD * 2;      // 8.4 MB  (-> part1)
  const size_t SZ_P3   = (size_t)NN * DD * 2;      // 8.4 MB  (part3)
  const size_t NEEDED  = SZ_P + SZ_X0 + SZ_WHT + SZ_HB + SZ_WB + SZ_U + SZ_P3 + 2 * (size_t)NN * 4;

  if (ws_size < NEEDED) {
    fill_kernel<<<256, 256, 0, stream>>>(out, out_size, 12345.0f);
    return;
  }

  char* ws = (char*)d_ws;
  size_t off = 0;
  u16*   P    = (u16*)(ws + off); off += SZ_P;
  u16*   x0   = (u16*)(ws + off); off += SZ_X0;
  u16*   WhT  = (u16*)(ws + off); off += SZ_WHT;
  u16*   hb   = (u16*)(ws + off); off += SZ_HB;
  u16*   Wb   = (u16*)(ws + off); off += SZ_WB;
  u16*   U    = (u16*)(ws + off); off += SZ_U;
  u16*   p3   = (u16*)(ws + off); off += SZ_P3;
  float* invn = (float*)(ws + off);
  float* den  = invn + NN;

  // Wh fp32 (16.8 MB) aliases the P prefix: dead before sim writes P.
  float* Wh = (float*)P;
  // split-K partials reuse regions dead after the sim-GEMM:
  u16* part0 = x0;
  u16* part1 = U;
  u16* part2 = hb;
  u16* part3 = p3;

  cvt4_kernel<<<1024, 256, 0, stream>>>((const float4*)h, (ushort4*)hb, NN * DD / 4);
  cvt4_kernel<<<256, 256, 0, stream>>>((const float4*)W, (ushort4*)Wb, DD * DD / 4);
  // Wh = h @ W^T
  gemm_wh<<<dim3(DD / 128, NN / 128), 256, 0, stream>>>(hb, Wb, DD, DD, Wh);
  rownorm_kernel<<<NN, 64, 0, stream>>>(Wh, invn, den);
  u_wht_kernel<<<dim3(NN / 64, DD / 64), 256, 0, stream>>>(Wh, invn, U, WhT);
  // P = mask ? exp(U U^T) : 0 (bf16), full grid, 1-barrier/tile ring, fused den
  gemm_sim<<<dim3(NN / 128, NN / 128), 256, 0, stream>>>(U, adj, P, den);
  // out partials: 256x256 tile, phase-split counted-vmcnt schedule, split-K=4
  gemm_out2<<<dim3(NN / 256, DD / 256, 4), 512, 0, stream>>>(P, WhT, part0, part1, part2, part3);
  // out = (p0+p1+p2+p3) / den
  reduce4_kernel<<<NN * DD / 8 / 256, 256, 0, stream>>>(
      (const uint4*)part0, (const uint4*)part1, (const uint4*)part2, (const uint4*)part3,
      den, (float4*)out);
}

// Round 10
// 569.808 us; speedup vs baseline: 1.0172x; 1.0010x over previous
//
#include <hip/hip_runtime.h>
#include <hip/hip_bf16.h>
#include <stdint.h>

#define NN 8192
#define DD 512

typedef unsigned short u16;
typedef __attribute__((ext_vector_type(8))) short short8;
typedef __attribute__((ext_vector_type(4))) float f32x4;

// async global->LDS, 16B per lane; LDS dest = wave-uniform base + lane*16
__device__ __forceinline__ void gld_lds16(const void* g, void* l) {
  __builtin_amdgcn_global_load_lds(
      (const __attribute__((address_space(1))) uint32_t*)(uintptr_t)g,
      (__attribute__((address_space(3))) uint32_t*)(uintptr_t)l,
      16, 0, 0);
}

__device__ __forceinline__ u16 f2bf(float f) {
  __hip_bfloat16 b = __float2bfloat16(f);
  return __builtin_bit_cast(u16, b);
}

__global__ void fill_kernel(float* __restrict__ p, int n, float v) {
  int i = blockIdx.x * 256 + threadIdx.x;
  int stride = gridDim.x * 256;
  for (; i < n; i += stride) p[i] = v;
}

__global__ void cvt4_kernel(const float4* __restrict__ src, ushort4* __restrict__ dst, int n4) {
  int i = blockIdx.x * 256 + threadIdx.x;
  int stride = gridDim.x * 256;
  for (; i < n4; i += stride) {
    float4 v = src[i];
    ushort4 o;
    o.x = f2bf(v.x); o.y = f2bf(v.y); o.z = f2bf(v.z); o.w = f2bf(v.w);
    dst[i] = o;
  }
}

// one wave per row: 1/||Wh_i||; also zeroes den[row]
__global__ void rownorm_kernel(const float* __restrict__ Wh, float* __restrict__ invn,
                               float* __restrict__ den) {
  int row = blockIdx.x;
  int l = threadIdx.x;  // 64
  const float4* p = (const float4*)(Wh + (size_t)row * DD);
  float4 a = p[l], b = p[l + 64];
  float s = a.x*a.x + a.y*a.y + a.z*a.z + a.w*a.w
          + b.x*b.x + b.y*b.y + b.z*b.z + b.w*b.w;
  #pragma unroll
  for (int off = 32; off; off >>= 1) s += __shfl_down(s, off);
  if (l == 0) {
    invn[row] = 1.0f / sqrtf(s);
    den[row] = 0.0f;
  }
}

// 64x64 tile: U = bf16(Wh * invn) (row-major) and WhT = bf16(Wh)^T
__global__ void u_wht_kernel(const float* __restrict__ Wh, const float* __restrict__ invn,
                             u16* __restrict__ U, u16* __restrict__ WhT) {
  __shared__ float tile[64][65];
  int i0 = blockIdx.x * 64, d0 = blockIdx.y * 64;
  int c = threadIdx.x & 63, rb = threadIdx.x >> 6;
  #pragma unroll
  for (int r = rb; r < 64; r += 4) {
    float v = Wh[(size_t)(i0 + r) * DD + d0 + c];
    tile[r][c] = v;
    U[(size_t)(i0 + r) * DD + d0 + c] = f2bf(v * invn[i0 + r]);
  }
  __syncthreads();
  #pragma unroll
  for (int r = rb; r < 64; r += 4) {
    WhT[(size_t)(d0 + r) * NN + i0 + c] = f2bf(tile[c][r]);
  }
}

// Wh-GEMM: C = A * B^T fp32, A:[M x K], B:[Nn x K] bf16. 128x128 tile, 256 thr.
__global__ void __launch_bounds__(256) gemm_wh(
    const u16* __restrict__ A, const u16* __restrict__ B,
    int Nn, int K, float* __restrict__ Cf)
{
  __shared__ __align__(16) u16 As[128 * 32];
  __shared__ __align__(16) u16 Bs[128 * 32];

  const int tid = threadIdx.x;
  const int w = tid >> 6;
  const int lane = tid & 63;
  const int lm = lane & 15;
  const int q = lane >> 4;
  const int row0 = blockIdx.y * 128;
  const int col0 = blockIdx.x * 128;
  const int RM = (w >> 1) * 64;
  const int RN = (w & 1) * 64;
  const int sr = tid >> 2;
  const int sk = (tid & 3) * 8;

  f32x4 acc[4][4];
  #pragma unroll
  for (int a_ = 0; a_ < 4; a_++)
    #pragma unroll
    for (int b_ = 0; b_ < 4; b_++)
      acc[a_][b_] = (f32x4){0.f, 0.f, 0.f, 0.f};

  const size_t Abase = (size_t)row0 * K;
  const size_t Bbase = (size_t)col0 * K;

  for (int k0 = 0; k0 < K; k0 += 32) {
    __syncthreads();
    gld_lds16(A + Abase + (size_t)sr * K + k0 + sk,        (char*)As + w * 1024);
    gld_lds16(A + Abase + (size_t)(sr + 64) * K + k0 + sk, (char*)As + 4096 + w * 1024);
    gld_lds16(B + Bbase + (size_t)sr * K + k0 + sk,        (char*)Bs + w * 1024);
    gld_lds16(B + Bbase + (size_t)(sr + 64) * K + k0 + sk, (char*)Bs + 4096 + w * 1024);
    __syncthreads();

    short8 af[4], bfr[4];
    #pragma unroll
    for (int mt = 0; mt < 4; mt++)
      af[mt] = *(const short8*)&As[(RM + mt * 16 + lm) * 32 + q * 8];
    #pragma unroll
    for (int nt = 0; nt < 4; nt++)
      bfr[nt] = *(const short8*)&Bs[(RN + nt * 16 + lm) * 32 + q * 8];

    #pragma unroll
    for (int mt = 0; mt < 4; mt++)
      #pragma unroll
      for (int nt = 0; nt < 4; nt++)
        acc[mt][nt] = __builtin_amdgcn_mfma_f32_16x16x32_bf16(af[mt], bfr[nt], acc[mt][nt], 0, 0, 0);
  }

  #pragma unroll
  for (int mt = 0; mt < 4; mt++) {
    const int ib = row0 + RM + mt * 16 + q * 4;
    #pragma unroll
    for (int rr = 0; rr < 4; rr++) {
      const int i = ib + rr;
      #pragma unroll
      for (int nt = 0; nt < 4; nt++) {
        const int jc = col0 + RN + nt * 16 + lm;
        Cf[(size_t)i * Nn + jc] = acc[mt][nt][rr];
      }
    }
  }
}

// sim-GEMM v8: v7 (1-barrier 4-deep ring) + XCD-pinning block swizzle.
// Mechanism: default dispatch round-robins consecutive blocks across 8 XCDs, so
// no XCD L2 (4 MB) holds a stable U panel set -> the ~1 GB of U re-reads are
// L3-served (~450cyc) instead of L2 (~200cyc). Remap (assuming XCD = s%8,
// perf-heuristic only): XCD x owns bj in [8x,8x+8) for ALL bi, walked in 8x8
// squares -> per-XCD working set = 8 B-panels (1 MB, pinned) + 8 A-panels
// (1 MB window) = 2 MB < 4 MB L2 -> all U re-reads become L2 hits.
// Bijection: x=bj/8, q8=bi/8, r=(bi%8)*8+(bj%8), s=(q8*64+r)*8+x.
__global__ void __launch_bounds__(256, 2) gemm_sim(
    const u16* __restrict__ U, const int* __restrict__ adj,
    u16* __restrict__ Pb, float* __restrict__ den)
{
  __shared__ __align__(16) char lds[65536];  // ring buf b at b*16384: A 8KB | B 8KB

  // XCD-pinning swizzle (pure index permutation; correctness-neutral)
  const int s = blockIdx.y * 64 + blockIdx.x;  // global linear index, 0..4095
  const int x  = s & 7;                        // presumed XCD (round-robin)
  const int g  = s >> 3;                       // 0..511 within XCD
  const int q8 = g >> 6;                       // 0..7: A-square window
  const int r  = g & 63;
  const int bi = q8 * 8 + (r >> 3);
  const int bj = x * 8 + (r & 7);

  const int tid = threadIdx.x;
  const int w = tid >> 6;
  const int lane = tid & 63;
  const int lm = lane & 15;
  const int q = lane >> 4;
  const int row0 = bi * 128;
  const int col0 = bj * 128;
  const int RM = (w >> 1) * 64;
  const int RN = (w & 1) * 64;
  const bool diag = (bi == bj);

  const u16* Ab = U + (size_t)row0 * DD;
  const u16* Bb = U + (size_t)col0 * DD;

  const int srow = tid >> 2;                                  // 0..63
  const int sch8 = (((tid & 3) ^ ((tid >> 3) & 3)) << 3);     // element offset
  const int wofs = w << 10;                                   // per-wave LDS base

  const int rA = RM + lm;
  const int rB = RN + lm;
  const int aoff = rA * 64 + ((q ^ ((rA >> 1) & 3)) << 4);
  const int boff = 8192 + rB * 64 + ((q ^ ((rB >> 1) & 3)) << 4);

  f32x4 acc[4][4];
  #pragma unroll
  for (int a_ = 0; a_ < 4; a_++)
    #pragma unroll
    for (int b_ = 0; b_ < 4; b_++)
      acc[a_][b_] = (f32x4){0.f, 0.f, 0.f, 0.f};

  // adj batch-0 prefetch: oldest VMEM ops; drained by the prologue vmcnt(8)
  int na0[4][4], na1[4][4];
  {
    const int ib0 = row0 + RM + q * 4;
    #pragma unroll
    for (int rr = 0; rr < 4; rr++)
      #pragma unroll
      for (int nt = 0; nt < 4; nt++)
        na0[rr][nt] = adj[(size_t)(ib0 + rr) * NN + col0 + RN + nt * 16 + lm];
  }
  asm volatile("" ::: "memory");

#define SSTAGE(koff, dstoff)                                                      \
  do {                                                                            \
    char* d_ = lds + (dstoff);                                                    \
    gld_lds16(Ab + (size_t)srow * DD + (koff) + sch8,        d_ + wofs);          \
    gld_lds16(Ab + (size_t)(srow + 64) * DD + (koff) + sch8, d_ + 4096 + wofs);   \
    gld_lds16(Bb + (size_t)srow * DD + (koff) + sch8,        d_ + 8192 + wofs);   \
    gld_lds16(Bb + (size_t)(srow + 64) * DD + (koff) + sch8, d_ + 12288 + wofs);  \
  } while (0)

  // prologue: tiles 0..2 -> bufs 0..2 (buf3 first written by tile0's stage).
  // vmcnt(8) drains adj(16)+stage0, leaves stage1+stage2 (newest 8) in flight.
  SSTAGE(0, 0);
  SSTAGE(32, 16384);
  SSTAGE(64, 32768);
  asm volatile("s_waitcnt vmcnt(8)" ::: "memory");
  asm volatile("s_barrier" ::: "memory");

  // Tile T: reads(buf T&3); stage(T+3 -> buf (T+3)&3); lgkm0; 16 MFMA;
  // vmcnt(VMC: T+1's stage complete); barrier.
#define STILE(T, CBOFF, SBOFF, DOSTAGE, VMC)                                      \
  do {                                                                            \
    const char* cb = lds + (CBOFF);                                               \
    short8 af[4], bfr[4];                                                         \
    _Pragma("unroll")                                                             \
    for (int m = 0; m < 4; m++)                                                   \
      af[m] = *(const short8*)(cb + aoff + m * 1024);                             \
    _Pragma("unroll")                                                             \
    for (int n = 0; n < 4; n++)                                                   \
      bfr[n] = *(const short8*)(cb + boff + n * 1024);                            \
    if (DOSTAGE) SSTAGE(((T) + 3) * 32, (SBOFF));                                 \
    asm volatile("s_waitcnt lgkmcnt(0)" ::: "memory");                            \
    __builtin_amdgcn_s_setprio(1);                                                \
    _Pragma("unroll")                                                             \
    for (int m = 0; m < 4; m++)                                                   \
      _Pragma("unroll")                                                           \
      for (int n = 0; n < 4; n++)                                                 \
        acc[m][n] = __builtin_amdgcn_mfma_f32_16x16x32_bf16(af[m], bfr[n], acc[m][n], 0, 0, 0); \
    __builtin_amdgcn_s_setprio(0);                                                \
    asm volatile("s_waitcnt " VMC ::: "memory");                                  \
    asm volatile("s_barrier" ::: "memory");                                       \
  } while (0)

  #pragma unroll 1
  for (int t = 0; t < 12; t += 4) {
    STILE(t + 0, 0,     49152, 1, "vmcnt(8)");
    STILE(t + 1, 16384, 0,     1, "vmcnt(8)");
    STILE(t + 2, 32768, 16384, 1, "vmcnt(8)");
    STILE(t + 3, 49152, 32768, 1, "vmcnt(8)");
  }
  STILE(12, 0,     49152, 1, "vmcnt(8)");
  STILE(13, 16384, 0,     0, "vmcnt(4)");
  STILE(14, 32768, 0,     0, "vmcnt(0)");
  STILE(15, 49152, 0,     0, "vmcnt(0)");
#undef STILE
#undef SSTAGE

  // epilogue: C/D layout col = lm, row = q*4 + rr; adj batches pipelined 1-deep
#define EPI(MT, NAC, NAN, DOLOAD)                                                 \
  do {                                                                            \
    if (DOLOAD) {                                                                 \
      const int ibn = row0 + RM + ((MT) + 1) * 16 + q * 4;                        \
      _Pragma("unroll")                                                           \
      for (int rr = 0; rr < 4; rr++)                                              \
        _Pragma("unroll")                                                         \
        for (int nt = 0; nt < 4; nt++)                                            \
          NAN[rr][nt] = adj[(size_t)(ibn + rr) * NN + col0 + RN + nt * 16 + lm];  \
    }                                                                             \
    const int ibc = row0 + RM + (MT) * 16 + q * 4;                                \
    _Pragma("unroll")                                                             \
    for (int rr = 0; rr < 4; rr++) {                                              \
      const int i = ibc + rr;                                                     \
      float psum = 0.f;                                                           \
      _Pragma("unroll")                                                           \
      for (int nt = 0; nt < 4; nt++) {                                            \
        const int jc = col0 + RN + nt * 16 + lm;                                  \
        const float ev = __expf(acc[MT][nt][rr]);                                 \
        const bool on = (NAC[rr][nt] != 0) || (diag && i == jc);                  \
        const float p = on ? ev : 0.0f;                                           \
        psum += p;                                                                \
        Pb[(size_t)i * NN + jc] = f2bf(p);                                        \
      }                                                                           \
      _Pragma("unroll")                                                           \
      for (int off = 8; off; off >>= 1) psum += __shfl_down(psum, off, 16);       \
      if (lm == 0) atomicAdd(&den[i], psum);                                      \
    }                                                                             \
  } while (0)

  EPI(0, na0, na1, 1);
  EPI(1, na1, na0, 1);
  EPI(2, na0, na1, 1);
  EPI(3, na1, na0, 0);
#undef EPI
}

// out-GEMM v2 (best): 256x256 tile, BK=32, 8 waves, split-K=4.
// P's second read is L3-served (134 MB < 256 MB L3). Counted vmcnt(4),
// XOR chunk swizzle both-sides, setprio.
__global__ void __launch_bounds__(512, 2) gemm_out2(
    const u16* __restrict__ P_,   // P [NN x NN]
    const u16* __restrict__ Wt,   // WhT [DD x NN]
    u16* __restrict__ p0, u16* __restrict__ p1,
    u16* __restrict__ p2, u16* __restrict__ p3)
{
  __shared__ __align__(16) char lds[65536];  // buf b at b*32768: A 16KB | B 16KB

  const int tid = threadIdx.x;
  const int lane = tid & 63;
  const int lm = lane & 15;
  const int q = lane >> 4;
  const int w = tid >> 6;       // 0..7
  const int wm = w >> 2;        // 0..1 -> 128 rows
  const int wn = w & 3;         // 0..3 -> 64 cols
  const int row0 = blockIdx.x * 256;   // i block
  const int col0 = blockIdx.y * 256;   // d block
  const int z = blockIdx.z;            // split-K
  const int kBegin = z * (NN / 4);
  const int NT = (NN / 4) / 32;        // 64 K-tiles

  const u16* Ab = P_ + (size_t)row0 * NN;
  const u16* Bb = Wt + (size_t)col0 * NN;

  const int srow = tid >> 2;                                  // 0..127
  const int sch8 = (((tid & 3) ^ ((tid >> 3) & 3)) << 3);     // element offset
  const int wofs = (tid >> 6) << 10;                          // per-wave LDS base

  const int rA = wm * 128 + lm;
  const int rB = wn * 64 + lm;
  const int aoff = rA * 64 + ((q ^ ((rA >> 1) & 3)) << 4);
  const int boff = 16384 + rB * 64 + ((q ^ ((rB >> 1) & 3)) << 4);

  f32x4 acc[8][4];
  #pragma unroll
  for (int m = 0; m < 8; m++)
    #pragma unroll
    for (int n = 0; n < 4; n++)
      acc[m][n] = (f32x4){0.f, 0.f, 0.f, 0.f};

#define STAGE4(koff, dstoff)                                                      \
  do {                                                                            \
    char* d_ = lds + (dstoff);                                                    \
    gld_lds16(Ab + (size_t)srow * NN + (koff) + sch8,         d_ + wofs);         \
    gld_lds16(Ab + (size_t)(srow + 128) * NN + (koff) + sch8, d_ + 8192 + wofs);  \
    gld_lds16(Bb + (size_t)srow * NN + (koff) + sch8,         d_ + 16384 + wofs); \
    gld_lds16(Bb + (size_t)(srow + 128) * NN + (koff) + sch8, d_ + 24576 + wofs); \
  } while (0)

  STAGE4(kBegin, 0);
  STAGE4(kBegin + 32, 32768);
  asm volatile("s_waitcnt vmcnt(4)" ::: "memory");
  asm volatile("s_barrier" ::: "memory");

#define TILE(T, CBOFF)                                                            \
  do {                                                                            \
    const char* cb = lds + (CBOFF);                                               \
    short8 af[8], bf_[4];                                                         \
    _Pragma("unroll")                                                             \
    for (int m = 0; m < 8; m++)                                                   \
      af[m] = *(const short8*)(cb + aoff + m * 1024);                             \
    _Pragma("unroll")                                                             \
    for (int n = 0; n < 4; n++)                                                   \
      bf_[n] = *(const short8*)(cb + boff + n * 1024);                            \
    asm volatile("s_barrier" ::: "memory");                                       \
    asm volatile("s_waitcnt lgkmcnt(0)" ::: "memory");                            \
    __builtin_amdgcn_s_setprio(1);                                                \
    _Pragma("unroll")                                                             \
    for (int m = 0; m < 4; m++)                                                   \
      _Pragma("unroll")                                                           \
      for (int n = 0; n < 4; n++)                                                 \
        acc[m][n] = __builtin_amdgcn_mfma_f32_16x16x32_bf16(af[m], bf_[n], acc[m][n], 0, 0, 0); \
    __builtin_amdgcn_s_setprio(0);                                                \
    asm volatile("s_barrier" ::: "memory");                                       \
    if ((T) + 2 < NT) STAGE4(kBegin + ((T) + 2) * 32, CBOFF);                     \
    asm volatile("s_barrier" ::: "memory");                                       \
    __builtin_amdgcn_s_setprio(1);                                                \
    _Pragma("unroll")                                                             \
    for (int m = 4; m < 8; m++)                                                   \
      _Pragma("unroll")                                                           \
      for (int n = 0; n < 4; n++)                                                 \
        acc[m][n] = __builtin_amdgcn_mfma_f32_16x16x32_bf16(af[m], bf_[n], acc[m][n], 0, 0, 0); \
    __builtin_amdgcn_s_setprio(0);                                                \
    if ((T) + 2 < NT) { asm volatile("s_waitcnt vmcnt(4)" ::: "memory"); }        \
    else              { asm volatile("s_waitcnt vmcnt(0)" ::: "memory"); }        \
    asm volatile("s_barrier" ::: "memory");                                       \
  } while (0)

  #pragma unroll 1
  for (int t = 0; t < NT; t += 2) {
    TILE(t, 0);
    TILE(t + 1, 32768);
  }
#undef TILE
#undef STAGE4

  u16* const part = (z == 0) ? p0 : (z == 1) ? p1 : (z == 2) ? p2 : p3;
  #pragma unroll
  for (int m = 0; m < 8; m++) {
    const int ib = row0 + wm * 128 + m * 16 + q * 4;
    #pragma unroll
    for (int rr = 0; rr < 4; rr++) {
      const int i = ib + rr;
      #pragma unroll
      for (int n = 0; n < 4; n++) {
        const int dc = col0 + wn * 64 + n * 16 + lm;
        part[(size_t)i * DD + dc] = f2bf(acc[m][n][rr]);
      }
    }
  }
}

// out = (sum of 4 bf16 partials) / den[row]; each thread handles 8 cols
__global__ void reduce4_kernel(const uint4* __restrict__ p0, const uint4* __restrict__ p1,
                               const uint4* __restrict__ p2, const uint4* __restrict__ p3,
                               const float* __restrict__ den, float4* __restrict__ out) {
  const int idx = blockIdx.x * 256 + threadIdx.x;   // NN*DD/8 units of 8 cols
  const int row = idx >> 6;                          // 64 units per row
  const float dinv = 1.0f / den[row];
  float s[8] = {0, 0, 0, 0, 0, 0, 0, 0};
  #pragma unroll
  for (int zp = 0; zp < 4; zp++) {
    const uint4 u = (zp == 0 ? p0 : zp == 1 ? p1 : zp == 2 ? p2 : p3)[idx];
    s[0] += __uint_as_float(u.x << 16); s[1] += __uint_as_float(u.x & 0xffff0000u);
    s[2] += __uint_as_float(u.y << 16); s[3] += __uint_as_float(u.y & 0xffff0000u);
    s[4] += __uint_as_float(u.z << 16); s[5] += __uint_as_float(u.z & 0xffff0000u);
    s[6] += __uint_as_float(u.w << 16); s[7] += __uint_as_float(u.w & 0xffff0000u);
  }
  float4 o0 = {s[0] * dinv, s[1] * dinv, s[2] * dinv, s[3] * dinv};
  float4 o1 = {s[4] * dinv, s[5] * dinv, s[6] * dinv, s[7] * dinv};
  out[idx * 2] = o0;
  out[idx * 2 + 1] = o1;
}

extern "C" void kernel_launch(void* const* d_in, const int* in_sizes, int n_in,
                              void* d_out, int out_size, void* d_ws, size_t ws_size,
                              hipStream_t stream) {
  const float* h = (const float*)d_in[0];
  const int* adj = (const int*)d_in[1];
  const float* W = (const float*)d_in[2];
  float* out = (float*)d_out;

  const size_t SZ_P    = (size_t)NN * NN * 2;      // 134.2 MB
  const size_t SZ_X0   = (size_t)NN * NN / 8;      // 8.4 MB  (-> part0)
  const size_t SZ_WHT  = (size_t)DD * NN * 2;      // 8.4 MB
  const size_t SZ_HB   = (size_t)NN * DD * 2;      // 8.4 MB  (-> part2)
  const size_t SZ_WB   = (size_t)DD * DD * 2;      // 0.5 MB
  const size_t SZ_U    = (size_t)NN * DD * 2;      // 8.4 MB  (-> part1)
  const size_t SZ_P3   = (size_t)NN * DD * 2;      // 8.4 MB  (part3)
  const size_t NEEDED  = SZ_P + SZ_X0 + SZ_WHT + SZ_HB + SZ_WB + SZ_U + SZ_P3 + 2 * (size_t)NN * 4;

  if (ws_size < NEEDED) {
    fill_kernel<<<256, 256, 0, stream>>>(out, out_size, 12345.0f);
    return;
  }

  char* ws = (char*)d_ws;
  size_t off = 0;
  u16*   P    = (u16*)(ws + off); off += SZ_P;
  u16*   x0   = (u16*)(ws + off); off += SZ_X0;
  u16*   WhT  = (u16*)(ws + off); off += SZ_WHT;
  u16*   hb   = (u16*)(ws + off); off += SZ_HB;
  u16*   Wb   = (u16*)(ws + off); off += SZ_WB;
  u16*   U    = (u16*)(ws + off); off += SZ_U;
  u16*   p3   = (u16*)(ws + off); off += SZ_P3;
  float* invn = (float*)(ws + off);
  float* den  = invn + NN;

  // Wh fp32 (16.8 MB) aliases the P prefix: dead before sim writes P.
  float* Wh = (float*)P;
  // split-K partials reuse regions dead after the sim-GEMM:
  u16* part0 = x0;
  u16* part1 = U;
  u16* part2 = hb;
  u16* part3 = p3;

  cvt4_kernel<<<1024, 256, 0, stream>>>((const float4*)h, (ushort4*)hb, NN * DD / 4);
  cvt4_kernel<<<256, 256, 0, stream>>>((const float4*)W, (ushort4*)Wb, DD * DD / 4);
  // Wh = h @ W^T
  gemm_wh<<<dim3(DD / 128, NN / 128), 256, 0, stream>>>(hb, Wb, DD, DD, Wh);
  rownorm_kernel<<<NN, 64, 0, stream>>>(Wh, invn, den);
  u_wht_kernel<<<dim3(NN / 64, DD / 64), 256, 0, stream>>>(Wh, invn, U, WhT);
  // P = mask ? exp(U U^T) : 0 (bf16); XCD-pinned swizzle, 1-barrier ring, fused den
  gemm_sim<<<dim3(NN / 128, NN / 128), 256, 0, stream>>>(U, adj, P, den);
  // out partials: 256x256 tile, phase-split counted-vmcnt schedule, split-K=4
  gemm_out2<<<dim3(NN / 256, DD / 256, 4), 512, 0, stream>>>(P, WhT, part0, part1, part2, part3);
  // out = (p0+p1+p2+p3) / den
  reduce4_kernel<<<NN * DD / 8 / 256, 256, 0, stream>>>(
      (const uint4*)part0, (const uint4*)part1, (const uint4*)part2, (const uint4*)part3,
      den, (float4*)out);
}